// Round 1
// baseline (705.293 us; speedup 1.0000x reference)
//
#include <hip/hip_runtime.h>

// Problem constants (from reference): B=32, IN=16, C=8192, U=32, K=16, 3 routing iters.
#define CC   8192
#define UU   32
#define KK   16
#define BB   32
#define INU  16
#define UK   512      // U*K
#define CPB  32       // channels per block
#define NBLK 256      // CC / CPB  == CU count

// Fused routing pass:
//   inputs: x (B,IN,C), W (C,U,K,IN), v_in (B,U,K), b_io (C,U)
//   per c: u_hat[b,uk] = sum_i W[c,uk,i]*x[b,i,c]
//          a[c,u]  = (1/B) sum_{b,k} u_hat * v_in
//          b_new   = b_io + a ; e = exp(b_new) ; b_io <- b_new
//          Z[u]   += e ;  S[b,uk] += e * u_hat
// With v_in = 0 and b_io = 0 this reproduces iteration 1 exactly
// (e = 1 for all c => s = mean over c = softmax(0)-weighted sum).
__global__ __launch_bounds__(512, 2) void fused_pass(
    const float* __restrict__ x, const float* __restrict__ W,
    const float* __restrict__ v_in, float* __restrict__ b_io,
    float* __restrict__ S, float* __restrict__ Z)
{
    // x staged half-block at a time: [cc 0..15][bi 0..511], stride 516 floats
    // (pad 4 -> 16B-aligned rows, write conflicts <= 2-way which is free).
    __shared__ float xs[16 * 516];

    const int t   = threadIdx.x;   // uk = u*16 + k
    const int bid = blockIdx.x;
    const int c0  = bid * CPB;
    const int u   = t >> 4;
    const int k   = t & 15;

    // Per-thread register tiles over b.
    float v[BB], Sl[BB], uh[BB];
#pragma unroll
    for (int b = 0; b < BB; ++b) { v[b] = v_in[b * UK + t]; Sl[b] = 0.f; }
    float zloc = 0.f;

    // W row loader: 16 consecutive floats per (c, uk); wave reads 4KB contiguous
    // per float4 round -> fully coalesced; this IS the HBM stream.
    float4 w0, w1, w2, w3;
    {
        const float4* p = (const float4*)(W + ((size_t)c0 * UK + t) * INU);
        w0 = p[0]; w1 = p[1]; w2 = p[2]; w3 = p[3];
    }

    for (int cc = 0; cc < CPB; ++cc) {
        // Stage x for a 16-channel half: coalesced global reads, LDS broadcast later.
        if ((cc & 15) == 0) {
            __syncthreads();
            const int cbase = c0 + (cc & ~15);
            for (int j = 0; j < 16; ++j) {
                int idx = j * 512 + t;
                int ccl = idx & 15;
                int bi  = idx >> 4;
                xs[ccl * 516 + bi] = x[bi * CC + cbase + ccl];
            }
            __syncthreads();
        }

        // Prefetch next c's W row while computing this one.
        float4 n0, n1, n2, n3;
        const bool have_next = (cc + 1 < CPB);
        if (have_next) {
            const float4* p = (const float4*)(W + ((size_t)(c0 + cc + 1) * UK + t) * INU);
            n0 = p[0]; n1 = p[1]; n2 = p[2]; n3 = p[3];
        }

        const float* xrow = &xs[(cc & 15) * 516];
        float ap = 0.f;
#pragma unroll
        for (int b = 0; b < BB; ++b) {
            // broadcast ds_read_b128 x4 (all lanes same address -> conflict-free)
            const float4* xr = (const float4*)(xrow + b * INU);
            float4 x0 = xr[0], x1 = xr[1], x2 = xr[2], x3 = xr[3];
            float h;
            h = w0.x * x0.x;
            h = fmaf(w0.y, x0.y, h); h = fmaf(w0.z, x0.z, h); h = fmaf(w0.w, x0.w, h);
            h = fmaf(w1.x, x1.x, h); h = fmaf(w1.y, x1.y, h);
            h = fmaf(w1.z, x1.z, h); h = fmaf(w1.w, x1.w, h);
            h = fmaf(w2.x, x2.x, h); h = fmaf(w2.y, x2.y, h);
            h = fmaf(w2.z, x2.z, h); h = fmaf(w2.w, x2.w, h);
            h = fmaf(w3.x, x3.x, h); h = fmaf(w3.y, x3.y, h);
            h = fmaf(w3.z, x3.z, h); h = fmaf(w3.w, x3.w, h);
            uh[b] = h;
            ap = fmaf(h, v[b], ap);
        }

        // Reduce a over k: 16 lanes per u within the wave (t = u*16+k, k fast).
        ap += __shfl_xor(ap, 8);
        ap += __shfl_xor(ap, 4);
        ap += __shfl_xor(ap, 2);
        ap += __shfl_xor(ap, 1);

        const int c = c0 + cc;
        float bnew = b_io[c * UU + u] + ap * (1.0f / (float)BB);
        float e = __expf(bnew);
        zloc += e;
        if (k == 0) b_io[c * UU + u] = bnew;

#pragma unroll
        for (int b = 0; b < BB; ++b) Sl[b] = fmaf(e, uh[b], Sl[b]);

        if (have_next) { w0 = n0; w1 = n1; w2 = n2; w3 = n3; }
    }

    // Flush: 64 consecutive lanes -> consecutive addresses, coalesced atomics.
#pragma unroll
    for (int b = 0; b < BB; ++b) atomicAdd(S + b * UK + t, Sl[b]);
    if (k == 0) atomicAdd(Z + u, zloc);
}

// Normalize + squash: s = S/Z ; mag_sq[b,k] = sum_u s^2 (reference quirk: sum
// over the num_units axis) ; v = mag_sq/(1+mag_sq) * s/mag.
__global__ void squash_k(const float* __restrict__ S, const float* __restrict__ Z,
                         float* __restrict__ vout)
{
    __shared__ float z_sh[UU];
    __shared__ float s2_sh[UK];
    __shared__ float mag_sh[KK];

    const int b = blockIdx.x;   // 32 blocks
    const int t = threadIdx.x;  // 512 = uk

    if (t < UU) z_sh[t] = Z[t];
    float ssum = S[b * UK + t];
    __syncthreads();

    float s = ssum / z_sh[t >> 4];
    s2_sh[t] = s * s;
    __syncthreads();

    if (t < KK) {
        float m = 0.f;
        for (int uu = 0; uu < UU; ++uu) m += s2_sh[uu * KK + t];
        mag_sh[t] = m;
    }
    __syncthreads();

    float msq = mag_sh[t & 15];
    float out = (msq / (1.0f + msq)) * s / sqrtf(msq);
    vout[b * UK + t] = out;
}

extern "C" void kernel_launch(void* const* d_in, const int* in_sizes, int n_in,
                              void* d_out, int out_size, void* d_ws, size_t ws_size,
                              hipStream_t stream)
{
    const float* x = (const float*)d_in[0];   // (B, IN, C)
    const float* W = (const float*)d_in[1];   // (C, U, K, IN)
    float* out = (float*)d_out;               // (B, U, K, 1) fp32

    char* ws = (char*)d_ws;
    float* S   = (float*)(ws);                         // 64 KB
    float* Z   = (float*)(ws + 65536);                 // 128 B (padded to 256)
    float* vb  = (float*)(ws + 65536 + 256);           // 64 KB
    float* bio = (float*)(ws + 65536 + 256 + 65536);   // 1 MB

    hipMemsetAsync(vb,  0, BB * UK * 4, stream);
    hipMemsetAsync(bio, 0, CC * UU * 4, stream);

    for (int pass = 0; pass < 3; ++pass) {
        hipMemsetAsync(S, 0, BB * UK * 4, stream);
        hipMemsetAsync(Z, 0, UU * 4, stream);
        fused_pass<<<NBLK, 512, 0, stream>>>(x, W, vb, bio, S, Z);
        float* vo = (pass == 2) ? out : vb;
        squash_k<<<BB, UK, 0, stream>>>(S, Z, vo);
    }
}